// Round 3
// baseline (514.998 us; speedup 1.0000x reference)
//
#include <hip/hip_runtime.h>
#include <math.h>

// PPCALayer fused kernel, MI355X (gfx950) — persistent software-pipelined
// wave-autonomous version.
// x: [B=64, C=256, HW=3136] fp32, weight: [3136, 15] fp32, out same as x.
//
// Per pixel (b,s): 15 multi-scale channel-group means (scales 1,2,4,8 over
// contiguous channel groups) -> normalize across the 15 features (ddof=0)
// -> dot with weight[s,:] -> sigmoid -> scale x[b,:,s].
//
// R3 change vs R2: each wave now processes K_=8 consecutive 8-spatial tiles
// with a DOUBLE-BUFFERED register tile (A/B, 8 float4 each), issuing tile
// k+1's global loads before computing/storing tile k. Rationale: identical
// zero-barrier waves self-synchronize through the VMEM queue into
// read-burst / compute-lull / write-burst phases (R2 ~4.6 TB/s vs 6.6 TB/s
// pure-write fills). The rolling prefetch keeps reads in flight during every
// compute+store phase. Tile shrinks 16->8 spatials so both buffers fit:
// ~95 VGPRs -> still 4 waves/SIMD. Grid 784 blocks -> all waves resident.
//
// Lane layout (per tile): lane = (c0<<1)|s4.
//   c0 = lane>>1 in [0,32) owns channels [8*c0, 8*c0+8)
//   s4 = lane&1 owns spatials [4*s4, 4*s4+4) as one float4
// Butterfly distances 2,4,8,16,32 all preserve lane&1 (the spatial class).
// ZERO LDS, ZERO __syncthreads.
//
// Algebra (unchanged from R2): mean of the 15 features = tot/256 = the
// scale-1 feature, so its normalized value is 0 and weight[:,0] is dead.
// Distributed dot/variance with replication corrections: a lane's 32-group
// sum t1 is replicated on 4 lanes (x1/4), 64-group t2 on 8 (x1/8),
// 128-group t3 on 16 (x1/16).

constexpr int C_   = 256;
constexpr int HW_  = 3136;            // 56*56
constexpr int B_   = 64;
constexpr int SPW_ = 8;               // spatials per tile
constexpr int TPI_ = HW_ / SPW_;      // 392 tiles per image
constexpr int NT_  = B_ * TPI_;       // 25088 tiles total
constexpr int K_   = 8;               // tiles per wave (pipelined)
constexpr int WPB_ = 4;               // waves per block
constexpr int GRID_ = NT_ / (K_ * WPB_);  // 784 blocks -> all resident

__device__ __forceinline__ float4 shx4(float4 a, int m) {
  float4 r;
  r.x = __shfl_xor(a.x, m);
  r.y = __shfl_xor(a.y, m);
  r.z = __shfl_xor(a.z, m);
  r.w = __shfl_xor(a.w, m);
  return r;
}
__device__ __forceinline__ float4 add4(float4 a, float4 b) {
  float4 r; r.x = a.x + b.x; r.y = a.y + b.y; r.z = a.z + b.z; r.w = a.w + b.w;
  return r;
}

// Per-lane base pointer for tile t (also the store address).
__device__ __forceinline__ const float* tbase(const float* x, unsigned t,
                                              int c0, int s4) {
  const unsigned b   = t / TPI_;        // magic-mul, wave-uniform
  const unsigned til = t - b * TPI_;
  return x + (size_t)b * C_ * HW_ + (size_t)c0 * 8 * HW_
           + (size_t)(til * SPW_) + (size_t)(s4 << 2);
}

__device__ __forceinline__ void tload(float4 v[8], const float* x, unsigned t,
                                      int c0, int s4) {
  const float* p = tbase(x, t, c0, s4);
  #pragma unroll
  for (int i = 0; i < 8; ++i)
    v[i] = *(const float4*)(p + (size_t)i * HW_);
}

// Compute gate for tile t from v[], multiply, store.
__device__ __forceinline__ void tcs(float4 v[8], const float* __restrict__ x,
                                    const float* __restrict__ wgt,
                                    float* __restrict__ out, unsigned t,
                                    int c0, int s4) {
  // Channel-group sum hierarchy (per spatial component).
  float4 ps = v[0];
  #pragma unroll
  for (int i = 1; i < 8; ++i) ps = add4(ps, v[i]);   // 8-chan (own)
  const float4 p16 = add4(ps,  shx4(ps, 2));         // 16-chan
  const float4 t1  = add4(p16, shx4(p16, 4));        // 32-chan group sum
  const float4 t2  = add4(t1,  shx4(t1, 8));         // 64
  const float4 t3  = add4(t2,  shx4(t2, 16));        // 128
  const float4 t4  = add4(t3,  shx4(t3, 32));        // 256 (total)

  float4 m4;
  m4.x = t4.x * (1.f / 256.f); m4.y = t4.y * (1.f / 256.f);
  m4.z = t4.z * (1.f / 256.f); m4.w = t4.w * (1.f / 256.f);

  // Weight row block for this tile's 8 spatials; this lane covers 4 of them.
  const unsigned b   = t / TPI_;
  const unsigned til = t - b * TPI_;
  const int sp0 = (int)(til * SPW_);
  const float* wr = wgt + (size_t)(sp0 + (s4 << 2)) * 15;
  const int i128 = 1 + (c0 >> 4);   // feature idx: [0 dead, 1-2, 3-6, 7-14]
  const int i64  = 3 + (c0 >> 3);
  const int i32  = 7 + (c0 >> 2);

  float4 zn, sq;
#define DO_SPATIAL(J, T1c, T2c, T3c, Mc, ZNc, SQc)                           \
  {                                                                          \
    const float* wp = wr + (J) * 15;                                         \
    const float w128 = wp[i128];                                             \
    const float w64  = wp[i64];                                              \
    const float w32  = wp[i32];                                              \
    const float u1 = T1c * (1.f / 32.f)  - Mc;                               \
    const float u2 = T2c * (1.f / 64.f)  - Mc;                               \
    const float u3 = T3c * (1.f / 128.f) - Mc;                               \
    ZNc = u1 * w32 * 0.25f + u2 * w64 * 0.125f + u3 * w128 * 0.0625f;        \
    SQc = u1 * u1 * 0.25f  + u2 * u2 * 0.125f  + u3 * u3 * 0.0625f;          \
  }
  DO_SPATIAL(0, t1.x, t2.x, t3.x, m4.x, zn.x, sq.x)
  DO_SPATIAL(1, t1.y, t2.y, t3.y, m4.y, zn.y, sq.y)
  DO_SPATIAL(2, t1.z, t2.z, t3.z, m4.z, zn.z, sq.z)
  DO_SPATIAL(3, t1.w, t2.w, t3.w, m4.w, zn.w, sq.w)
#undef DO_SPATIAL

  // Sum accumulators across the 32 lanes sharing this spatial class.
  #pragma unroll
  for (int d = 2; d <= 32; d <<= 1) {
    zn = add4(zn, shx4(zn, d));
    sq = add4(sq, shx4(sq, d));
  }

  float4 g;
#define GATE(ZNc, SQc, Gc)                                                   \
  {                                                                          \
    const float inv = 1.f / sqrtf(SQc * (1.f / 15.f));                       \
    Gc = 1.f / (1.f + __expf(-(ZNc * inv)));                                 \
  }
  GATE(zn.x, sq.x, g.x)
  GATE(zn.y, sq.y, g.y)
  GATE(zn.z, sq.z, g.z)
  GATE(zn.w, sq.w, g.w)
#undef GATE

  float* ob = (float*)tbase(out, t, c0, s4);
  #pragma unroll
  for (int i = 0; i < 8; ++i) {
    float4 vv = v[i];
    vv.x *= g.x; vv.y *= g.y; vv.z *= g.z; vv.w *= g.w;
    *(float4*)(ob + (size_t)i * HW_) = vv;
  }
}

__global__ __launch_bounds__(256, 4) void ppca_fused(
    const float* __restrict__ x, const float* __restrict__ wgt,
    float* __restrict__ out)
{
  const int lane = threadIdx.x & 63;
  const int wav  = threadIdx.x >> 6;
  const int s4 = lane & 1;
  const int c0 = lane >> 1;

  const unsigned w  = blockIdx.x * WPB_ + wav;   // 0..3135
  const unsigned t0 = w * K_;                    // 8 consecutive tiles

  // Rolling 1-deep prefetch, statically double-buffered (rule #20: all
  // buffer indices compile-time constant).
  float4 A[8], Bv[8];
  tload(A,  x, t0 + 0, c0, s4);
  tload(Bv, x, t0 + 1, c0, s4);

  tcs(A,  x, wgt, out, t0 + 0, c0, s4); tload(A,  x, t0 + 2, c0, s4);
  tcs(Bv, x, wgt, out, t0 + 1, c0, s4); tload(Bv, x, t0 + 3, c0, s4);
  tcs(A,  x, wgt, out, t0 + 2, c0, s4); tload(A,  x, t0 + 4, c0, s4);
  tcs(Bv, x, wgt, out, t0 + 3, c0, s4); tload(Bv, x, t0 + 5, c0, s4);
  tcs(A,  x, wgt, out, t0 + 4, c0, s4); tload(A,  x, t0 + 6, c0, s4);
  tcs(Bv, x, wgt, out, t0 + 5, c0, s4); tload(Bv, x, t0 + 7, c0, s4);
  tcs(A,  x, wgt, out, t0 + 6, c0, s4);
  tcs(Bv, x, wgt, out, t0 + 7, c0, s4);
}

extern "C" void kernel_launch(void* const* d_in, const int* in_sizes, int n_in,
                              void* d_out, int out_size, void* d_ws, size_t ws_size,
                              hipStream_t stream) {
  const float* x = (const float*)d_in[0];      // [64,256,3136] fp32
  const float* w = (const float*)d_in[1];      // [3136,15] fp32
  float* out = (float*)d_out;                  // [64,256,3136] fp32
  (void)in_sizes; (void)n_in; (void)out_size; (void)d_ws; (void)ws_size;

  dim3 grid(GRID_);    // 784 blocks x 256 threads = 3136 waves, all resident
  dim3 block(256);
  ppca_fused<<<grid, block, 0, stream>>>(x, w, out);
}

// Round 4
// 355.293 us; speedup vs baseline: 1.4495x; 1.4495x over previous
//
#include <hip/hip_runtime.h>
#include <math.h>

// PPCALayer fused kernel, MI355X (gfx950) — wave-autonomous (R2 structure)
// + nontemporal single-touch streams + hoisted weight gather.
// x: [B=64, C=256, HW=3136] fp32, weight: [3136, 15] fp32, out same as x.
//
// Per pixel (b,s): 15 multi-scale channel-group means (scales 1,2,4,8 over
// contiguous channel groups) -> normalize across the 15 features (ddof=0)
// -> dot with weight[s,:] -> sigmoid -> scale x[b,:,s].
//
// Design (R2, measured ~91 us kernel): each WAVE owns 16 spatials x 256
// channels. lane = (c0<<2)|s4: c0=lane>>2 owns channels [16c0,16c0+16),
// s4=lane&3 owns 4 spatials as one float4. Tile (16 KB) lives in registers
// (16 x f32x4, kernel-body array -> SROA-promoted; NEVER pass it to helpers,
// R3's function-decay demoted it to scratch and doubled FETCH). Reductions
// are __shfl_xor butterflies (distances 4..32 preserve lane&3). ZERO LDS,
// ZERO barriers.
//
// R4 changes vs R2 (structure identical):
//  - __builtin_nontemporal_load/store for x/out: both streams are strictly
//    single-touch (412 MB) -> don't allocate in L2; weights stay cached.
//  - weight gather (3 floats x 4 spatials per lane, L2-resident) hoisted
//    BEFORE the 16 x-loads: removes the only L2-latency dependency inside
//    the post-load shuffle chain.
//
// Algebra: mean of the 15 features = tot/256 = scale-1 feature exactly, so
// its normalized value is 0 and weight[:,0] is dead. Distributed dot /
// variance with replication corrections (t1 on 2 lanes, t2 on 4, t3 on 8).

typedef float f32x4 __attribute__((ext_vector_type(4)));

constexpr int C_   = 256;
constexpr int HW_  = 3136;   // 56*56
constexpr int B_   = 64;
constexpr int SPW_ = 16;            // spatials per wave
constexpr int TPI_ = HW_ / SPW_;    // 196 tiles per image
constexpr int WPB_ = 4;             // waves per block (block = 256)

__device__ __forceinline__ f32x4 shx4(f32x4 a, int m) {
  f32x4 r;
  r.x = __shfl_xor(a.x, m);
  r.y = __shfl_xor(a.y, m);
  r.z = __shfl_xor(a.z, m);
  r.w = __shfl_xor(a.w, m);
  return r;
}

__global__ __launch_bounds__(256, 4) void ppca_fused(
    const float* __restrict__ x, const float* __restrict__ wgt,
    float* __restrict__ out)
{
  const int lane = threadIdx.x & 63;
  const int wav  = threadIdx.x >> 6;
  const unsigned W   = blockIdx.x * WPB_ + wav;   // 0..12543
  const unsigned b   = W / TPI_;                  // magic-mul div
  const unsigned til = W - b * TPI_;
  const int sp0 = til * SPW_;

  const int s4 = lane & 3;    // float4 column (4 spatials)
  const int c0 = lane >> 2;   // 16-channel group, 0..15

  const size_t off = (size_t)b * C_ * HW_ + (size_t)c0 * 16 * HW_
                   + (size_t)sp0 + (size_t)(s4 << 2);
  const float* xb = x + off;
  float* ob = out + off;

  // ---- Hoisted weight gather (L2-resident, reused 64x across batch).
  // Feature order in weight row: [0:tot(dead), 1-2:128s, 3-6:64s, 7-14:32s].
  const int i128 = 1 + (c0 >> 3);
  const int i64  = 3 + (c0 >> 2);
  const int i32  = 7 + (c0 >> 1);
  const float* wr = wgt + (size_t)(sp0 + (s4 << 2)) * 15;
  float w128v[4], w64v[4], w32v[4];
  #pragma unroll
  for (int j = 0; j < 4; ++j) {
    const float* wp = wr + j * 15;
    w128v[j] = wp[i128];
    w64v[j]  = wp[i64];
    w32v[j]  = wp[i32];
  }

  // ---- Load the wave's tile: 16 f32x4 per lane, registers only.
  // Per instruction: 16 channel rows x 64 B (4 lanes x 16 B), line-aligned.
  // Nontemporal: single-touch stream, don't allocate in L2.
  f32x4 v[16];
  #pragma unroll
  for (int i = 0; i < 16; ++i)
    v[i] = __builtin_nontemporal_load((const f32x4*)(xb + (size_t)i * HW_));

  // ---- Per-lane partial: sum of its 16 channels, per spatial component.
  f32x4 ps = v[0];
  #pragma unroll
  for (int i = 1; i < 16; ++i) ps += v[i];

  // ---- Butterfly up the group-sum hierarchy (per spatial component):
  // t1 = 32-group sum, t2 = 64-group, t3 = 128-group, t4 = total(256).
  const f32x4 t1 = ps + shx4(ps, 4);
  const f32x4 t2 = t1 + shx4(t1, 8);
  const f32x4 t3 = t2 + shx4(t2, 16);
  const f32x4 t4 = t3 + shx4(t3, 32);

  const f32x4 m4 = t4 * (1.f / 256.f);

  f32x4 zn, sq;
#define DO_SPATIAL(J, T1c, T2c, T3c, Mc, ZNc, SQc)                           \
  {                                                                          \
    const float u1 = T1c * (1.f / 32.f)  - Mc;                               \
    const float u2 = T2c * (1.f / 64.f)  - Mc;                               \
    const float u3 = T3c * (1.f / 128.f) - Mc;                               \
    ZNc = u1 * w32v[J] * 0.5f + u2 * w64v[J] * 0.25f                         \
        + u3 * w128v[J] * 0.125f;                                            \
    SQc = u1 * u1 * 0.5f + u2 * u2 * 0.25f + u3 * u3 * 0.125f;               \
  }
  DO_SPATIAL(0, t1.x, t2.x, t3.x, m4.x, zn.x, sq.x)
  DO_SPATIAL(1, t1.y, t2.y, t3.y, m4.y, zn.y, sq.y)
  DO_SPATIAL(2, t1.z, t2.z, t3.z, m4.z, zn.z, sq.z)
  DO_SPATIAL(3, t1.w, t2.w, t3.w, m4.w, zn.w, sq.w)
#undef DO_SPATIAL

  // ---- Butterfly-sum the accumulators across the 16 lanes sharing s4.
  #pragma unroll
  for (int d = 4; d <= 32; d <<= 1) {
    zn += shx4(zn, d);
    sq += shx4(sq, d);
  }

  // ---- Gate per spatial: var = sq/15; z = zn/std; gate = sigmoid(z).
  f32x4 g;
#define GATE(ZNc, SQc, Gc)                                                   \
  {                                                                          \
    const float inv = 1.f / sqrtf(SQc * (1.f / 15.f));                       \
    Gc = 1.f / (1.f + __expf(-(ZNc * inv)));                                 \
  }
  GATE(zn.x, sq.x, g.x)
  GATE(zn.y, sq.y, g.y)
  GATE(zn.z, sq.z, g.z)
  GATE(zn.w, sq.w, g.w)
#undef GATE

  // ---- Multiply registers by gate, nontemporal store (coalesced as load).
  #pragma unroll
  for (int i = 0; i < 16; ++i) {
    f32x4 vv = v[i];
    vv.x *= g.x; vv.y *= g.y; vv.z *= g.z; vv.w *= g.w;
    __builtin_nontemporal_store(vv, (f32x4*)(ob + (size_t)i * HW_));
  }
}

extern "C" void kernel_launch(void* const* d_in, const int* in_sizes, int n_in,
                              void* d_out, int out_size, void* d_ws, size_t ws_size,
                              hipStream_t stream) {
  const float* x = (const float*)d_in[0];      // [64,256,3136] fp32
  const float* w = (const float*)d_in[1];      // [3136,15] fp32
  float* out = (float*)d_out;                  // [64,256,3136] fp32
  (void)in_sizes; (void)n_in; (void)out_size; (void)d_ws; (void)ws_size;

  dim3 grid(B_ * TPI_ / WPB_);   // 12544 waves / 4 = 3136 blocks
  dim3 block(256);
  ppca_fused<<<grid, block, 0, stream>>>(x, w, out);
}